// Round 2
// baseline (113.337 us; speedup 1.0000x reference)
//
#include <hip/hip_runtime.h>

#define DK 256   // feature dim (K)
#define TT 1024  // T1 = T2
#define NB 16    // batch

typedef __attribute__((ext_vector_type(8))) short bf16x8;
typedef __attribute__((ext_vector_type(4))) float f32x4;

// round-to-nearest-even fp32 -> bf16 (inputs are finite normals)
__device__ __forceinline__ unsigned short f2bf(float f) {
    unsigned int u = __float_as_uint(f);
    unsigned int r = 0x7fffu + ((u >> 16) & 1u);
    return (unsigned short)((u + r) >> 16);
}

// ---------------------------------------------------------------------------
// Prep: xw = bf16(x * w3), yb = bf16(y), tx = x . w1, ty = y . w2
// One wave per row of 256 elements: lane handles float4 at d = lane*4.
// ---------------------------------------------------------------------------
__global__ __launch_bounds__(256) void prep_kernel(
    const float* __restrict__ x, const float* __restrict__ y,
    const float* __restrict__ WS,
    unsigned short* __restrict__ xw, unsigned short* __restrict__ yb,
    float* __restrict__ tx, float* __restrict__ ty)
{
    const int wid  = threadIdx.x >> 6;
    const int lane = threadIdx.x & 63;
    const int row  = blockIdx.x * 4 + wid;       // 0 .. 2*NB*TT-1 (wave-uniform)
    const bool is_x = row < NB * TT;
    const int r = is_x ? row : row - NB * TT;

    const float4 wmul = is_x ? ((const float4*)(WS + 2 * DK))[lane]
                             : make_float4(1.f, 1.f, 1.f, 1.f);
    const float4 wdot = is_x ? ((const float4*)WS)[lane]
                             : ((const float4*)(WS + DK))[lane];

    const float4 v = ((const float4*)((is_x ? x : y) + (size_t)r * DK))[lane];

    float partial = v.x * wdot.x + v.y * wdot.y + v.z * wdot.z + v.w * wdot.w;

    ushort4 o;
    o.x = f2bf(v.x * wmul.x);
    o.y = f2bf(v.y * wmul.y);
    o.z = f2bf(v.z * wmul.z);
    o.w = f2bf(v.w * wmul.w);
    ((ushort4*)((is_x ? xw : yb) + (size_t)r * DK))[lane] = o;

    #pragma unroll
    for (int off = 32; off > 0; off >>= 1)
        partial += __shfl_down(partial, off);
    if (lane == 0) (is_x ? tx : ty)[r] = partial;
}

// ---------------------------------------------------------------------------
// GEMM: out[b, i, j] = sum_k xw[b,i,k] * yb[b,j,k] + tx[b,i] + ty[b,j]
// 128x128 tile, BK=64, double-buffered LDS (2x32KB = 64KB), ONE barrier/kt.
// stage(kt+1) is issued BEFORE compute(kt) so the vmcnt drain at the next
// barrier finds the loads already complete.
// LDS layout per tile-row m: 16B chunk kc stored at slot (kc ^ (m & 7)) ->
// global_load_lds dest stays wave-uniform-base + lane*16, ds_read_b128
// fragment reads are conflict-free (2-way max = free).
// ---------------------------------------------------------------------------
__device__ __forceinline__ void gl_lds16(const unsigned short* g,
                                         unsigned short* l)
{
    __builtin_amdgcn_global_load_lds(
        (const __attribute__((address_space(1))) void*)g,
        (__attribute__((address_space(3))) void*)l,
        16, 0, 0);
}

__global__ __launch_bounds__(256) void gemm_kernel(
    const unsigned short* __restrict__ xw, const unsigned short* __restrict__ yb,
    const float* __restrict__ tx, const float* __restrict__ ty,
    float* __restrict__ out)
{
    __shared__ unsigned short As[2][128 * 64];   // 2 x 16 KB
    __shared__ unsigned short Bs[2][128 * 64];   // 2 x 16 KB  -> 64 KB total

    const int tid  = threadIdx.x;
    const int w    = tid >> 6;
    const int lane = tid & 63;
    const int wi   = w >> 1;      // wave row (0..1)
    const int wj   = w & 1;       // wave col (0..1)
    const int batch = blockIdx.z;
    const int it = blockIdx.y;    // i tile (0..7)
    const int jt = blockIdx.x;    // j tile (0..7)

    const unsigned short* gA = xw + ((size_t)batch * TT + it * 128) * DK;
    const unsigned short* gB = yb + ((size_t)batch * TT + jt * 128) * DK;

    // staging geometry (loop-invariant)
    const int sm0_base = w * 32;            // wave's row base (uniform)
    const int srow     = lane >> 3;         // row within 8-row group
    const int sslot    = lane & 7;          // LDS 16B chunk slot

    f32x4 acc[4][4];
    #pragma unroll
    for (int i = 0; i < 4; ++i)
        #pragma unroll
        for (int j = 0; j < 4; ++j)
            acc[i][j] = (f32x4){0.f, 0.f, 0.f, 0.f};

    const int mfr  = lane & 15;   // row/col within 16x16 fragment
    const int quad = lane >> 4;

    // ---- prologue: stage kt=0 into buffer 0
    #pragma unroll
    for (int q = 0; q < 4; ++q) {
        const int m0 = sm0_base + q * 8;
        const int m  = m0 + srow;
        const int kc = sslot ^ (m & 7);
        gl_lds16(gA + (size_t)m * DK + kc * 8, &As[0][m0 * 64]);
        gl_lds16(gB + (size_t)m * DK + kc * 8, &Bs[0][m0 * 64]);
    }

    #pragma unroll
    for (int kt = 0; kt < 4; ++kt) {
        __syncthreads();   // drains stage(kt); also releases buf[(kt+1)&1]

        // ---- prefetch kt+1 into the other buffer (overlaps compute below)
        if (kt < 3) {
            const int buf = (kt + 1) & 1;
            #pragma unroll
            for (int q = 0; q < 4; ++q) {
                const int m0 = sm0_base + q * 8;
                const int m  = m0 + srow;
                const int kc = sslot ^ (m & 7);
                gl_lds16(gA + (size_t)m * DK + (kt + 1) * 64 + kc * 8,
                         &As[buf][m0 * 64]);
                gl_lds16(gB + (size_t)m * DK + (kt + 1) * 64 + kc * 8,
                         &Bs[buf][m0 * 64]);
            }
        }

        // ---- compute kt: 2 MFMA K-steps of 32
        const unsigned short* Ab = As[kt & 1];
        const unsigned short* Bb = Bs[kt & 1];
        #pragma unroll
        for (int ks = 0; ks < 2; ++ks) {
            const int kc = ks * 4 + quad;           // 16B chunk this quad reads
            bf16x8 av[4], bv[4];
            #pragma unroll
            for (int mi = 0; mi < 4; ++mi) {
                const int m = wi * 64 + mi * 16 + mfr;
                av[mi] = *(const bf16x8*)(Ab + m * 64 + (kc ^ (m & 7)) * 8);
                const int n = wj * 64 + mi * 16 + mfr;
                bv[mi] = *(const bf16x8*)(Bb + n * 64 + (kc ^ (n & 7)) * 8);
            }
            #pragma unroll
            for (int mi = 0; mi < 4; ++mi)
                #pragma unroll
                for (int ni = 0; ni < 4; ++ni)
                    acc[mi][ni] = __builtin_amdgcn_mfma_f32_16x16x32_bf16(
                        av[mi], bv[ni], acc[mi][ni], 0, 0, 0);
        }
    }

    // ---- epilogue: + tx[i] + ty[j], fp32 store (tx/ty straight from L2)
    const float* txp = tx + batch * TT + it * 128;
    const float* typ = ty + batch * TT + jt * 128;
    float tyv[4];
    #pragma unroll
    for (int ni = 0; ni < 4; ++ni)
        tyv[ni] = typ[wj * 64 + ni * 16 + mfr];

    float* outB = out + ((size_t)batch << 20) + (size_t)(it * 128) * TT + jt * 128;
    #pragma unroll
    for (int mi = 0; mi < 4; ++mi) {
        #pragma unroll
        for (int r = 0; r < 4; ++r) {
            const int row  = wi * 64 + mi * 16 + quad * 4 + r;
            const float trow = txp[row];
            #pragma unroll
            for (int ni = 0; ni < 4; ++ni) {
                const int col = wj * 64 + ni * 16 + mfr;
                outB[(size_t)row * TT + col] = acc[mi][ni][r] + trow + tyv[ni];
            }
        }
    }
}

// ---------------------------------------------------------------------------
// Fallback (only if workspace too small): naive fp32, correctness net.
// ---------------------------------------------------------------------------
__global__ __launch_bounds__(256) void naive_kernel(
    const float* __restrict__ x, const float* __restrict__ y,
    const float* __restrict__ WS, float* __restrict__ out)
{
    size_t idx = (size_t)blockIdx.x * 256 + threadIdx.x;
    if (idx >= (size_t)NB * TT * TT) return;
    const int b = (int)(idx >> 20);
    const int i = (int)((idx >> 10) & (TT - 1));
    const int j = (int)(idx & (TT - 1));
    const float* xp = x + ((size_t)b * TT + i) * DK;
    const float* yp = y + ((size_t)b * TT + j) * DK;
    float s = 0.f, sx = 0.f, sy = 0.f;
    for (int d = 0; d < DK; ++d) {
        const float xv = xp[d], yv = yp[d];
        s  += xv * WS[2 * DK + d] * yv;
        sx += xv * WS[d];
        sy += yv * WS[DK + d];
    }
    out[idx] = s + sx + sy;
}

extern "C" void kernel_launch(void* const* d_in, const int* in_sizes, int n_in,
                              void* d_out, int out_size, void* d_ws, size_t ws_size,
                              hipStream_t stream)
{
    const float* x  = (const float*)d_in[0];
    const float* y  = (const float*)d_in[1];
    const float* WS = (const float*)d_in[2];
    float* out = (float*)d_out;

    const size_t n_xy = (size_t)NB * TT * DK;           // 4,194,304 elements
    const size_t need = n_xy * 2 * sizeof(unsigned short)   // xw + yb
                      + (size_t)NB * TT * 2 * sizeof(float); // tx + ty

    if (ws_size >= need) {
        unsigned short* xw = (unsigned short*)d_ws;
        unsigned short* yb = xw + n_xy;
        float* tx = (float*)(yb + n_xy);
        float* ty = tx + NB * TT;

        prep_kernel<<<dim3((2 * NB * TT) / 4), dim3(256), 0, stream>>>(
            x, y, WS, xw, yb, tx, ty);
        gemm_kernel<<<dim3(8, 8, NB), dim3(256), 0, stream>>>(
            xw, yb, tx, ty, out);
    } else {
        naive_kernel<<<dim3((NB * TT * TT + 255) / 256), dim3(256), 0, stream>>>(
            x, y, WS, out);
    }
}

// Round 3
// 111.036 us; speedup vs baseline: 1.0207x; 1.0207x over previous
//
#include <hip/hip_runtime.h>

#define DK 256   // feature dim (K)
#define TT 1024  // T1 = T2
#define NB 16    // batch

typedef __attribute__((ext_vector_type(8))) short bf16x8;
typedef __attribute__((ext_vector_type(4))) float f32x4;

// round-to-nearest-even fp32 -> bf16 (inputs are finite normals)
__device__ __forceinline__ unsigned short f2bf(float f) {
    unsigned int u = __float_as_uint(f);
    unsigned int r = 0x7fffu + ((u >> 16) & 1u);
    return (unsigned short)((u + r) >> 16);
}

// ---------------------------------------------------------------------------
// Prep: xw = bf16(x * w3), yb = bf16(y), tx = x . w1, ty = y . w2
// One wave per row of 256 elements: lane handles float4 at d = lane*4.
// ---------------------------------------------------------------------------
__global__ __launch_bounds__(256) void prep_kernel(
    const float* __restrict__ x, const float* __restrict__ y,
    const float* __restrict__ WS,
    unsigned short* __restrict__ xw, unsigned short* __restrict__ yb,
    float* __restrict__ tx, float* __restrict__ ty)
{
    const int wid  = threadIdx.x >> 6;
    const int lane = threadIdx.x & 63;
    const int row  = blockIdx.x * 4 + wid;       // 0 .. 2*NB*TT-1 (wave-uniform)
    const bool is_x = row < NB * TT;
    const int r = is_x ? row : row - NB * TT;

    const float4 wmul = is_x ? ((const float4*)(WS + 2 * DK))[lane]
                             : make_float4(1.f, 1.f, 1.f, 1.f);
    const float4 wdot = is_x ? ((const float4*)WS)[lane]
                             : ((const float4*)(WS + DK))[lane];

    const float4 v = ((const float4*)((is_x ? x : y) + (size_t)r * DK))[lane];

    float partial = v.x * wdot.x + v.y * wdot.y + v.z * wdot.z + v.w * wdot.w;

    ushort4 o;
    o.x = f2bf(v.x * wmul.x);
    o.y = f2bf(v.y * wmul.y);
    o.z = f2bf(v.z * wmul.z);
    o.w = f2bf(v.w * wmul.w);
    ((ushort4*)((is_x ? xw : yb) + (size_t)r * DK))[lane] = o;

    #pragma unroll
    for (int off = 32; off > 0; off >>= 1)
        partial += __shfl_down(partial, off);
    if (lane == 0) (is_x ? tx : ty)[r] = partial;
}

// ---------------------------------------------------------------------------
// GEMM, B-stationary: out[b,i,j] = sum_k xw[b,i,k]*yb[b,j,k] + tx[b,i] + ty[b,j]
//
// Each block: stage full B-tile (128 j x 256 k bf16 = 64 KB LDS) ONCE via
// global_load_lds; ONE barrier total. Then each wave owns 64 i-rows and
// streams A fragments global->VGPR (no LDS, no barriers in the K-loop ->
// compiler hoists loads with fine-grained vmcnt; hipBLASLt-style overlap).
// acc = 64x128 per wave = 128 VGPRs.
//
// B LDS layout: row j (512 B = 32 chunks of 16 B); chunk c stored at slot
// c ^ (j & 7). Swizzle applied on the glds SOURCE address so the LDS dest
// stays wave-uniform-base + lane*16 (HW constraint). XOR within 128 B keeps
// global coalescing; fragment ds_read_b128 is conflict-free (8 accesses/bank).
// ---------------------------------------------------------------------------
__device__ __forceinline__ void gl_lds16(const unsigned short* g,
                                         unsigned short* l)
{
    __builtin_amdgcn_global_load_lds(
        (const __attribute__((address_space(1))) void*)g,
        (__attribute__((address_space(3))) void*)l,
        16, 0, 0);
}

__global__ __launch_bounds__(256, 2) void gemm_kernel(
    const unsigned short* __restrict__ xw, const unsigned short* __restrict__ yb,
    const float* __restrict__ tx, const float* __restrict__ ty,
    float* __restrict__ out)
{
    __shared__ unsigned short Bs[128 * DK];      // 64 KB, full K

    const int tid  = threadIdx.x;
    const int w    = tid >> 6;
    const int lane = tid & 63;
    const int jt = blockIdx.x;    // j tile (0..7), 128 cols
    const int is = blockIdx.y;    // i slice (0..3), 256 rows
    const int b  = blockIdx.z;    // batch

    const unsigned short* gB = yb + ((size_t)b * TT + jt * 128) * DK;

    // ---- stage B-tile once: 4096 16B-chunks, 64 wave-instructions total
    #pragma unroll
    for (int q = 0; q < 16; ++q) {
        const int g = w * 16 + q;           // chunk group = 2 rows (uniform)
        const int j = g * 2 + (lane >> 5);  // local row
        const int s = lane & 31;            // LDS slot within row
        const int c = s ^ (j & 7);          // global chunk for this slot
        gl_lds16(gB + j * DK + c * 8, Bs + g * 512);
    }
    __syncthreads();                        // the ONLY barrier

    const int mfr  = lane & 15;
    const int quad = lane >> 4;
    const int i0   = is * 256 + w * 64;     // wave's 64-row i-base
    const unsigned short* gA = xw + ((size_t)b * TT + i0) * DK;

    f32x4 acc[4][8];
    #pragma unroll
    for (int it = 0; it < 4; ++it)
        #pragma unroll
        for (int n = 0; n < 8; ++n)
            acc[it][n] = (f32x4){0.f, 0.f, 0.f, 0.f};

    // ---- barrier-free K-loop: A from global, B-frags from LDS (1 read : 4 MFMA)
    #pragma unroll
    for (int ks = 0; ks < 8; ++ks) {
        bf16x8 av[4];
        #pragma unroll
        for (int it = 0; it < 4; ++it)
            av[it] = *(const bf16x8*)(gA + (size_t)(it * 16 + mfr) * DK
                                      + ks * 32 + quad * 8);
        #pragma unroll
        for (int n = 0; n < 8; ++n) {
            const int j    = n * 16 + mfr;
            const int slot = (ks * 4 + quad) ^ (j & 7);
            const bf16x8 bv = *(const bf16x8*)(Bs + j * DK + slot * 8);
            #pragma unroll
            for (int it = 0; it < 4; ++it)
                acc[it][n] = __builtin_amdgcn_mfma_f32_16x16x32_bf16(
                    av[it], bv, acc[it][n], 0, 0, 0);
        }
    }

    // ---- epilogue: + tx[i] + ty[j], fp32 stores
    const float* txp = tx + b * TT + i0;
    const float* typ = ty + b * TT + jt * 128;
    float tyv[8];
    #pragma unroll
    for (int n = 0; n < 8; ++n)
        tyv[n] = typ[n * 16 + mfr];

    float* outB = out + ((size_t)b << 20) + (size_t)i0 * TT + jt * 128;
    #pragma unroll
    for (int it = 0; it < 4; ++it) {
        #pragma unroll
        for (int r = 0; r < 4; ++r) {
            const int row  = it * 16 + quad * 4 + r;
            const float trow = txp[row];
            #pragma unroll
            for (int n = 0; n < 8; ++n)
                outB[(size_t)row * TT + n * 16 + mfr] = acc[it][n][r] + trow + tyv[n];
        }
    }
}

// ---------------------------------------------------------------------------
// Fallback (only if workspace too small): naive fp32, correctness net.
// ---------------------------------------------------------------------------
__global__ __launch_bounds__(256) void naive_kernel(
    const float* __restrict__ x, const float* __restrict__ y,
    const float* __restrict__ WS, float* __restrict__ out)
{
    size_t idx = (size_t)blockIdx.x * 256 + threadIdx.x;
    if (idx >= (size_t)NB * TT * TT) return;
    const int b = (int)(idx >> 20);
    const int i = (int)((idx >> 10) & (TT - 1));
    const int j = (int)(idx & (TT - 1));
    const float* xp = x + ((size_t)b * TT + i) * DK;
    const float* yp = y + ((size_t)b * TT + j) * DK;
    float s = 0.f, sx = 0.f, sy = 0.f;
    for (int d = 0; d < DK; ++d) {
        const float xv = xp[d], yv = yp[d];
        s  += xv * WS[2 * DK + d] * yv;
        sx += xv * WS[d];
        sy += yv * WS[DK + d];
    }
    out[idx] = s + sx + sy;
}

extern "C" void kernel_launch(void* const* d_in, const int* in_sizes, int n_in,
                              void* d_out, int out_size, void* d_ws, size_t ws_size,
                              hipStream_t stream)
{
    const float* x  = (const float*)d_in[0];
    const float* y  = (const float*)d_in[1];
    const float* WS = (const float*)d_in[2];
    float* out = (float*)d_out;

    const size_t n_xy = (size_t)NB * TT * DK;           // 4,194,304 elements
    const size_t need = n_xy * 2 * sizeof(unsigned short)   // xw + yb
                      + (size_t)NB * TT * 2 * sizeof(float); // tx + ty

    if (ws_size >= need) {
        unsigned short* xw = (unsigned short*)d_ws;
        unsigned short* yb = xw + n_xy;
        float* tx = (float*)(yb + n_xy);
        float* ty = tx + NB * TT;

        prep_kernel<<<dim3((2 * NB * TT) / 4), dim3(256), 0, stream>>>(
            x, y, WS, xw, yb, tx, ty);
        gemm_kernel<<<dim3(8, 4, NB), dim3(256), 0, stream>>>(
            xw, yb, tx, ty, out);
    } else {
        naive_kernel<<<dim3((NB * TT * TT + 255) / 256), dim3(256), 0, stream>>>(
            x, y, WS, out);
    }
}